// Round 2
// 66.106 us; speedup vs baseline: 1.0006x; 1.0006x over previous
//
#include <hip/hip_runtime.h>

// Problem constants (from reference setup_inputs)
static constexpr int kA = 128;   // atoms
static constexpr int kN = 64;    // neighbors
static constexpr int kG = 16;    // grid size per axis
static constexpr int kC = 10;    // channels = 5 types x 2 grid lengths
static constexpr int kS = 17;    // padded LDS row stride (+1: bank-conflict-free staging)

// out[b=0][a][c][x][y][z], c = type_idx*2 + length_idx
// Per channel (Z, L):
//   out = sum_{n: Z_n == Z} exp(coeff*||g - d_n||^2) + (N - cnt_Z) * exp(coeff*|g|^2)
// (reference masks d, not the exp). Separable: exp = ex*ey*ez.
//
// Round-5 (resubmit; previous bench died to container-acquisition failure):
// LDS bank-conflict-free staging.
//   Old: row stride 16, thread t -> (n=t/3, ax=t%3). Each ds_write_b32 put all
//   64 lanes on banks {i, i+16} (bank = (16n+i)%32) -> ~32-way conflict x 16
//   writes x 3 waves, serialized on the LDS pipe *before* the barrier.
//   New: row stride 17 (odd -> 17n mod 32 bijective) and ownership
//   (ax = t>>6, n = t&63): one wave per axis, banks (17n+i)%32 hit each bank
//   exactly twice (n, n+32) -> 2-way = free (m136).
//   Reads stay conflict-free: ey[n*17+y] = 16 consecutive banks; ex wave-
//   uniform (broadcast); ez becomes 4x ds_read_b32 (17-stride breaks 16B
//   alignment for b128) - negligible on ~4 matched neighbors/block.
// Store epilogue unchanged from round-4 (fully-coalesced 1 KB/wave float4s).

__global__ __launch_bounds__(256) void voxel_kernel(
    const float* __restrict__ dvec,   // (1, A, N, 3) fp32
    const float* __restrict__ sigma,  // (1,) fp32
    const int*   __restrict__ zn,     // (A, N) int32
    float*       __restrict__ out)    // (1, A, 10, G, G, G) fp32
{
    const int blk = blockIdx.x;          // a*10 + c,  c = ch*2 + li
    const int a   = blk / 10;
    const int c   = blk - a * 10;
    const int ch  = c >> 1;
    const int li  = c & 1;

    const int Ztab[5] = {1, 6, 7, 8, 16};
    const int Ztarget = Ztab[ch];

    const float Lg   = li ? 12.0f : 8.0f;
    const float step = Lg * (1.0f / 15.0f);
    const float t0   = -0.5f * Lg;
    const float sg   = sigma[0];
    const float coeff = -0.5f / (sg * sg);

    const int t = threadIdx.x;           // 0..255

    __shared__ float s_tab[3 * kN * kS]; // [axis][n][tick(+pad)], ~12.75 KB
    __shared__ float s_e0[kG];           // exp(coeff*tick^2)

    // --- Stage separable tables: wave ax (=t>>6) owns axis ax, lane owns n.
    //     Global read per wave is a 768 B span (stride 12 B) - L2-resident
    //     (dvec is 98 KB total, re-read by 10 blocks/atom).
    if (t < 192) {
        const int ax = t >> 6;           // wave id 0..2 = axis
        const int n  = t & 63;
        const float d = dvec[(size_t)a * (kN * 3) + n * 3 + ax];
        float* dst = &s_tab[(ax * kN + n) * kS];
#pragma unroll
        for (int i = 0; i < kG; ++i) {
            const float r = (t0 + i * step) - d;
            dst[i] = __expf(coeff * r * r);   // bank (17n+i)%32 -> 2-way, free
        }
    } else if (t < 192 + kG) {
        const int i = t - 192;
        const float r = t0 + i * step;
        s_e0[i] = __expf(coeff * r * r);
    }

    // --- Classification: per-wave ballot; mask identical in every wave.
    const int lane = t & 63;
    const int Zl   = zn[a * kN + lane];
    unsigned long long mask = __ballot(Zl == Ztarget);
    const int cnt = __popcll(mask);

    __syncthreads();

    // Ownership mapping (round-4): float4 #(t + 256q) = (x=t>>6+4q,
    // y=(t>>2)&15, z=4*(t&3)..+3).
    const int y  = (t >> 2) & 15;
    const int zq = (t & 3) * 4;
    const int xb = t >> 6;               // wave id; x_i = xb + 4i

    const float* s_ex = &s_tab[0 * kN * kS];
    const float* s_ey = &s_tab[1 * kN * kS];
    const float* s_ez = &s_tab[2 * kN * kS];

    // --- Origin-centered term via the s_e0 table.
    float acc[4][4];
    {
        const float w  = (float)(kN - cnt) * s_e0[y];
        float ez0[4];
#pragma unroll
        for (int j = 0; j < 4; ++j) ez0[j] = s_e0[zq + j];
#pragma unroll
        for (int i = 0; i < 4; ++i) {
            const float wx = w * s_e0[xb + 4 * i];
#pragma unroll
            for (int j = 0; j < 4; ++j)
                acc[i][j] = wx * ez0[j];
        }
    }

    // --- Matched neighbors: iterate set bits of the SGPR mask.
    while (mask) {
        const int n = (int)__builtin_ctzll(mask);   // wave-uniform
        mask &= mask - 1ull;
        const int nS = n * kS;
        const float eyn = s_ey[nS + y];             // 16 consecutive banks
        float ezn[4];
#pragma unroll
        for (int j = 0; j < 4; ++j) ezn[j] = s_ez[nS + zq + j];  // 4x b32, free
#pragma unroll
        for (int i = 0; i < 4; ++i) {
            const float p = s_ex[nS + xb + 4 * i] * eyn;  // s_ex wave-uniform
#pragma unroll
            for (int j = 0; j < 4; ++j)
                acc[i][j] = fmaf(p, ezn[j], acc[i][j]);
        }
    }

    // --- Fully-coalesced store: per instruction q, lane l writes float4
    //     #(wave*64 + l + 256q) - contiguous 1 KB per wave, full lines.
    float4* o = (float4*)(out + ((size_t)a * kC + c) * (kG * kG * kG));
#pragma unroll
    for (int q = 0; q < 4; ++q)
        o[t + 256 * q] = make_float4(acc[q][0], acc[q][1], acc[q][2], acc[q][3]);
}

extern "C" void kernel_launch(void* const* d_in, const int* in_sizes, int n_in,
                              void* d_out, int out_size, void* d_ws, size_t ws_size,
                              hipStream_t stream) {
    const float* dvec  = (const float*)d_in[0];   // distance_vector (1,128,64,3) fp32
    const float* sigma = (const float*)d_in[1];   // sigma (1,) fp32
    const int*   zn    = (const int*)d_in[2];     // atomic_numbers (128,64) int32
    float* out = (float*)d_out;                   // (1,128,10,16,16,16) fp32

    voxel_kernel<<<dim3(kA * kC), dim3(256), 0, stream>>>(dvec, sigma, zn, out);
}

// Round 3
// 65.853 us; speedup vs baseline: 1.0044x; 1.0038x over previous
//
#include <hip/hip_runtime.h>

// Problem constants (from reference setup_inputs)
static constexpr int kA = 128;   // atoms
static constexpr int kN = 64;    // neighbors
static constexpr int kG = 16;    // grid size per axis
static constexpr int kC = 10;    // channels = 5 types x 2 grid lengths
static constexpr int kS = 17;    // padded LDS row stride (bank-conflict-free)

// out[b=0][a][c][x][y][z], c = type_idx*2 + length_idx
// Per channel (Z, L):
//   out = sum_{n: Z_n == Z} exp(coeff*||g - d_n||^2) + (N - cnt_Z) * exp(coeff*|g|^2)
// Separable: exp = ex*ey*ez.
//
// Round-6: channel fusion — the exp tables s_tab depend only on (a, li), not
// on the atom type, so the previous 10-blocks-per-atom layout recomputed the
// identical 12.75 KB table 5x. New grid: one block per (a, li) = 256 blocks,
// 512 threads; stage once, then loop the 5 type-channels (5 ballots up
// front, one register acc[2][4] reused per channel). Total staging + exp
// work / dvec + zn traffic cut 5x; compute-loop and store totals unchanged.
// Discriminator: if dur_us doesn't move (two rounds already pinned at
// 66.1 +/- 0.04 across real kernel edits), the timed region is the harness
// floor (41.5 us poison fill at 80% HBM peak + fixed dispatch overhead) and
// the voxel kernel is off the critical path -> ROOFLINE.
//
// Thread->output mapping (512 threads, 2 float4/channel each): float4 index
// f = t + 512q, q in {0,1}: x = (t>>6) + 8q, y = (t>>2)&15, z = 4*(t&3)..+3.
// Per wave per q the 64 lanes write contiguous 1 KB (full lines). s_ex reads
// are wave-uniform (xb = wave id).

__global__ __launch_bounds__(512) void voxel_kernel(
    const float* __restrict__ dvec,   // (1, A, N, 3) fp32
    const float* __restrict__ sigma,  // (1,) fp32
    const int*   __restrict__ zn,     // (A, N) int32
    float*       __restrict__ out)    // (1, A, 10, G, G, G) fp32
{
    const int blk = blockIdx.x;          // a*2 + li
    const int a   = blk >> 1;
    const int li  = blk & 1;

    const float Lg   = li ? 12.0f : 8.0f;
    const float step = Lg * (1.0f / 15.0f);
    const float t0   = -0.5f * Lg;
    const float sg   = sigma[0];
    const float coeff = -0.5f / (sg * sg);

    const int t = threadIdx.x;           // 0..511

    __shared__ float s_tab[3 * kN * kS]; // [axis][n][tick(+pad)], ~12.75 KB
    __shared__ float s_e0[kG];           // exp(coeff*tick^2)

    // --- Stage separable tables once per (a, li): wave ax (=t>>6, ax<3)
    //     owns axis ax, lane owns n. Stride-17 rows: write banks (17n+i)%32
    //     are exactly 2-way per instruction (free, m136).
    if (t < 192) {
        const int ax = t >> 6;           // wave id 0..2 = axis
        const int n  = t & 63;
        const float d = dvec[(size_t)a * (kN * 3) + n * 3 + ax];
        float* dst = &s_tab[(ax * kN + n) * kS];
#pragma unroll
        for (int i = 0; i < kG; ++i) {
            const float r = (t0 + i * step) - d;
            dst[i] = __expf(coeff * r * r);
        }
    } else if (t < 192 + kG) {
        const int i = t - 192;
        const float r = t0 + i * step;
        s_e0[i] = __expf(coeff * r * r);
    }

    // --- Classification for all 5 types: per-wave ballots (identical in
    //     every wave; lane l reads zn[a*64 + l]).
    const int lane = t & 63;
    const int Zl   = zn[a * kN + lane];
    const int Ztab[5] = {1, 6, 7, 8, 16};
    unsigned long long masks[5];
    int cnts[5];
#pragma unroll
    for (int ch = 0; ch < 5; ++ch) {
        masks[ch] = __ballot(Zl == Ztab[ch]);
        cnts[ch]  = __popcll(masks[ch]);
    }

    __syncthreads();

    // Ownership mapping (see header).
    const int y  = (t >> 2) & 15;
    const int zq = (t & 3) * 4;
    const int xb = t >> 6;               // wave id 0..7; x_q = xb + 8q

    const float* s_ex = &s_tab[0 * kN * kS];
    const float* s_ey = &s_tab[1 * kN * kS];
    const float* s_ez = &s_tab[2 * kN * kS];

    // Origin-table factors hoisted out of the channel loop.
    const float e0y = s_e0[y];
    float e0x[2];
    e0x[0] = s_e0[xb];
    e0x[1] = s_e0[xb + 8];
    float ez0[4];
#pragma unroll
    for (int j = 0; j < 4; ++j) ez0[j] = s_e0[zq + j];

    // --- Per type-channel: origin term + matched-neighbor loop + store.
#pragma unroll
    for (int ch = 0; ch < 5; ++ch) {
        float acc[2][4];
        const float w = (float)(kN - cnts[ch]) * e0y;
#pragma unroll
        for (int i = 0; i < 2; ++i) {
            const float wx = w * e0x[i];
#pragma unroll
            for (int j = 0; j < 4; ++j)
                acc[i][j] = wx * ez0[j];
        }

        unsigned long long mask = masks[ch];
        while (mask) {
            const int n = (int)__builtin_ctzll(mask);   // wave-uniform
            mask &= mask - 1ull;
            const int nS = n * kS;
            const float eyn = s_ey[nS + y];             // 16 consecutive banks
            float ezn[4];
#pragma unroll
            for (int j = 0; j < 4; ++j) ezn[j] = s_ez[nS + zq + j];
#pragma unroll
            for (int i = 0; i < 2; ++i) {
                const float p = s_ex[nS + xb + 8 * i] * eyn;  // wave-uniform
#pragma unroll
                for (int j = 0; j < 4; ++j)
                    acc[i][j] = fmaf(p, ezn[j], acc[i][j]);
            }
        }

        // Fully-coalesced store: per instruction q, the wave writes a
        // contiguous 1 KB run of channel c.
        const int c = ch * 2 + li;
        float4* o = (float4*)(out + ((size_t)a * kC + c) * (kG * kG * kG));
#pragma unroll
        for (int q = 0; q < 2; ++q)
            o[t + 512 * q] = make_float4(acc[q][0], acc[q][1], acc[q][2], acc[q][3]);
    }
}

extern "C" void kernel_launch(void* const* d_in, const int* in_sizes, int n_in,
                              void* d_out, int out_size, void* d_ws, size_t ws_size,
                              hipStream_t stream) {
    const float* dvec  = (const float*)d_in[0];   // distance_vector (1,128,64,3) fp32
    const float* sigma = (const float*)d_in[1];   // sigma (1,) fp32
    const int*   zn    = (const int*)d_in[2];     // atomic_numbers (128,64) int32
    float* out = (float*)d_out;                   // (1,128,10,16,16,16) fp32

    voxel_kernel<<<dim3(kA * 2), dim3(512), 0, stream>>>(dvec, sigma, zn, out);
}